// Round 1
// baseline (3944.129 us; speedup 1.0000x reference)
//
#include <hip/hip_runtime.h>
#include <cstddef>

#define NSAMP 16
#define HW 409600
#define CPRED 6
#define NBINS 65536
#define BPS 100           // blocks per sample for big passes (100*256*16 = 409600)
#define EPS 1e-6

__device__ __forceinline__ unsigned sortkey(float f) {
    unsigned b = __float_as_uint(f);
    return (b & 0x80000000u) ? ~b : (b | 0x80000000u);   // larger float -> larger key
}
__device__ __forceinline__ float inv_sortkey(unsigned k) {
    unsigned b = (k & 0x80000000u) ? (k ^ 0x80000000u) : ~k;
    return __uint_as_float(b);
}
__device__ __forceinline__ float sigmoidf(float x) {
    return 1.0f / (1.0f + __expf(-x));
}

// Pass 1: pos count, neg count, hi-16-bit histogram of negative pred keys.
__global__ void k_stats(const float* __restrict__ preds,
                        const float* __restrict__ targets,
                        const float* __restrict__ eff,
                        unsigned* __restrict__ hist,
                        unsigned* __restrict__ pos,
                        unsigned* __restrict__ negc) {
    const int n = blockIdx.y;
    const float4* p4 = (const float4*)(preds + (size_t)n * CPRED * HW);
    const float4* t4 = (const float4*)(targets + (size_t)n * 2 * HW);
    const float4* e4 = (const float4*)(eff + (size_t)n * HW);
    unsigned* h = hist + (size_t)n * NBINS;
    unsigned lp = 0, ln = 0;
    const int base = blockIdx.x * 1024;
#pragma unroll
    for (int k = 0; k < 4; k++) {
        int i = base + k * 256 + threadIdx.x;
        float4 p = p4[i], t = t4[i], e = e4[i];
        float pa[4] = {p.x, p.y, p.z, p.w};
        float ta[4] = {t.x, t.y, t.z, t.w};
        float ea[4] = {e.x, e.y, e.z, e.w};
#pragma unroll
        for (int j = 0; j < 4; j++) {
            lp += (ta[j] > 0.5f && ea[j] > 0.5f) ? 1u : 0u;
            if (ta[j] <= 0.5f) {
                ln++;
                atomicAdd(&h[sortkey(pa[j]) >> 16], 1u);
            }
        }
    }
    for (int off = 32; off; off >>= 1) {
        lp += __shfl_down(lp, off, 64);
        ln += __shfl_down(ln, off, 64);
    }
    if ((threadIdx.x & 63) == 0) {
        atomicAdd(&pos[n], lp);
        atomicAdd(&negc[n], ln);
    }
}

// Pass 2: find hi bucket containing the neg_num-th largest; zero hist for reuse.
__global__ void k_scan_hi(unsigned* __restrict__ hist,
                          const unsigned* __restrict__ pos,
                          const unsigned* __restrict__ negc,
                          unsigned* __restrict__ bucket,
                          unsigned* __restrict__ rem,
                          unsigned* __restrict__ fb) {
    const int n = blockIdx.x;
    unsigned* h = hist + (size_t)n * NBINS;
    __shared__ unsigned chunkSum[256];
    __shared__ unsigned s_bucket, s_rem;
    const unsigned p = pos[n], nc = negc[n];
    const unsigned long long nn =
        min((unsigned long long)p * 3ull, (unsigned long long)nc);
    const bool fallback = (p == 0) || (nn == 0);

    unsigned s = 0;
    const int cbase = threadIdx.x * 256;
    for (int i = 0; i < 256; i++) s += h[cbase + i];
    chunkSum[threadIdx.x] = s;
    if (threadIdx.x == 0) { s_bucket = 0xFFFFFFFFu; s_rem = 0; }
    __syncthreads();

    if (threadIdx.x == 0 && !fallback) {
        unsigned long long cum = 0;
        int c;
        for (c = 255; c >= 0; c--) {
            if (cum + chunkSum[c] >= nn) break;
            cum += chunkSum[c];
        }
        for (int b = c * 256 + 255;; b--) {
            unsigned hv = h[b];
            if (cum + hv >= nn) { s_bucket = (unsigned)b; s_rem = (unsigned)(nn - cum); break; }
            cum += hv;
        }
    }
    __syncthreads();   // ensure thread 0 done reading h before zeroing
    for (int i = threadIdx.x; i < NBINS; i += blockDim.x) h[i] = 0;
    if (threadIdx.x == 0) {
        bucket[n] = s_bucket;
        rem[n] = s_rem;
        fb[n] = fallback ? 1u : 0u;
    }
}

// Pass 3: lo-16-bit histogram for elements in the chosen hi bucket.
__global__ void k_refine(const float* __restrict__ preds,
                         const float* __restrict__ targets,
                         const unsigned* __restrict__ bucket,
                         unsigned* __restrict__ hist) {
    const int n = blockIdx.y;
    const unsigned bkt = bucket[n];
    if (bkt == 0xFFFFFFFFu) return;   // fallback sample
    const float4* p4 = (const float4*)(preds + (size_t)n * CPRED * HW);
    const float4* t4 = (const float4*)(targets + (size_t)n * 2 * HW);
    unsigned* h = hist + (size_t)n * NBINS;
    const int base = blockIdx.x * 1024;
#pragma unroll
    for (int k = 0; k < 4; k++) {
        int i = base + k * 256 + threadIdx.x;
        float4 p = p4[i], t = t4[i];
        float pa[4] = {p.x, p.y, p.z, p.w};
        float ta[4] = {t.x, t.y, t.z, t.w};
#pragma unroll
        for (int j = 0; j < 4; j++) {
            if (ta[j] <= 0.5f) {
                unsigned key = sortkey(pa[j]);
                if ((key >> 16) == bkt) atomicAdd(&h[key & 0xFFFFu], 1u);
            }
        }
    }
}

// Pass 4: exact threshold from the lo histogram.
__global__ void k_scan_lo(const unsigned* __restrict__ hist,
                          const unsigned* __restrict__ bucket,
                          const unsigned* __restrict__ rem,
                          float* __restrict__ thr) {
    const int n = blockIdx.x;
    const unsigned bkt = bucket[n];
    if (threadIdx.x != 0) return;
    if (bkt == 0xFFFFFFFFu) { thr[n] = -INFINITY; return; }
    const unsigned* h = hist + (size_t)n * NBINS;
    const unsigned long long r = rem[n];
    unsigned long long cum = 0;
    for (int b = NBINS - 1;; b--) {
        unsigned hv = h[b];
        if (cum + hv >= r) {
            thr[n] = inv_sortkey((bkt << 16) | (unsigned)b);
            return;
        }
        cum += hv;
    }
}

// Pass 5: fused sigmoid + masks + 6 per-sample dice sums.
__global__ void k_dice(const float* __restrict__ preds,
                       const float* __restrict__ targets,
                       const float* __restrict__ eff,
                       const float* __restrict__ thr,
                       const unsigned* __restrict__ fb,
                       double* __restrict__ sums) {
    const int n = blockIdx.y;
    const float4* p0 = (const float4*)(preds + (size_t)n * CPRED * HW);
    const float4* p1 = (const float4*)(preds + (size_t)n * CPRED * HW + HW);
    const float4* t0 = (const float4*)(targets + (size_t)n * 2 * HW);
    const float4* t1 = (const float4*)(targets + (size_t)n * 2 * HW + HW);
    const float4* e4 = (const float4*)(eff + (size_t)n * HW);
    const float th = thr[n];
    const bool fallback = fb[n] != 0;
    float sPG = 0.f, sP2 = 0.f, sG2 = 0.f, sPGk = 0.f, sP2k = 0.f, sG2k = 0.f;
    const int base = blockIdx.x * 1024;
#pragma unroll
    for (int k = 0; k < 4; k++) {
        int i = base + k * 256 + threadIdx.x;
        float4 a = p0[i], b = p1[i], t = t0[i], u = t1[i], e = e4[i];
        float pa[4] = {a.x, a.y, a.z, a.w};
        float pb[4] = {b.x, b.y, b.z, b.w};
        float ta[4] = {t.x, t.y, t.z, t.w};
        float ua[4] = {u.x, u.y, u.z, u.w};
        float ea[4] = {e.x, e.y, e.z, e.w};
#pragma unroll
        for (int j = 0; j < 4; j++) {
            float pt = sigmoidf(pa[j]);
            float pk = sigmoidf(pb[j]);
            float tbt = (ta[j] > 0.5f) ? 1.f : 0.f;
            float tbk = (ua[j] > 0.5f) ? 1.f : 0.f;
            float m;
            if (fallback) m = ea[j];
            else m = (((pa[j] >= th) || (ta[j] > 0.5f)) && (ea[j] > 0.5f)) ? 1.f : 0.f;
            float Pm = pt * m, Tm = tbt * m;
            sPG += Pm * Tm; sP2 += Pm * Pm; sG2 += Tm * Tm;
            float mk = (pt > 0.5f && ea[j] > 0.5f) ? 1.f : 0.f;
            float Pk = pk * mk, Tk = tbk * mk;
            sPGk += Pk * Tk; sP2k += Pk * Pk; sG2k += Tk * Tk;
        }
    }
    for (int off = 32; off; off >>= 1) {
        sPG  += __shfl_down(sPG, off, 64);
        sP2  += __shfl_down(sP2, off, 64);
        sG2  += __shfl_down(sG2, off, 64);
        sPGk += __shfl_down(sPGk, off, 64);
        sP2k += __shfl_down(sP2k, off, 64);
        sG2k += __shfl_down(sG2k, off, 64);
    }
    if ((threadIdx.x & 63) == 0) {
        double* s = sums + (size_t)n * 6;
        atomicAdd(&s[0], (double)sPG);
        atomicAdd(&s[1], (double)sP2);
        atomicAdd(&s[2], (double)sG2);
        atomicAdd(&s[3], (double)sPGk);
        atomicAdd(&s[4], (double)sP2k);
        atomicAdd(&s[5], (double)sG2k);
    }
}

// Pass 6: 32 outputs.
__global__ void k_final(const double* __restrict__ sums, float* __restrict__ out) {
    int n = threadIdx.x;
    if (n < NSAMP) {
        const double* s = sums + (size_t)n * 6;
        out[n]         = (float)(1.0 - 2.0 * s[0] / (s[1] + s[2] + EPS));
        out[NSAMP + n] = (float)(1.0 - 2.0 * s[3] / (s[4] + s[5] + EPS));
    }
}

extern "C" void kernel_launch(void* const* d_in, const int* in_sizes, int n_in,
                              void* d_out, int out_size, void* d_ws, size_t ws_size,
                              hipStream_t stream) {
    const float* preds = (const float*)d_in[0];
    const float* targets = (const float*)d_in[1];
    const float* eff = (const float*)d_in[2];
    float* out = (float*)d_out;

    char* ws = (char*)d_ws;
    const size_t HIST_BYTES = (size_t)NSAMP * NBINS * sizeof(unsigned);  // 4 MiB
    unsigned* hist = (unsigned*)ws;
    unsigned* pos    = (unsigned*)(ws + HIST_BYTES);         // 16 u32
    unsigned* negc   = pos + NSAMP;
    unsigned* bucket = negc + NSAMP;
    unsigned* rem    = bucket + NSAMP;
    unsigned* fb     = rem + NSAMP;
    float*    thr    = (float*)(fb + NSAMP);
    double*   sums   = (double*)(ws + HIST_BYTES + 512);     // 8-aligned, 768 B

    // zero hist + counters + sums (required every call; harness does not re-poison)
    hipMemsetAsync(d_ws, 0, HIST_BYTES + 512 + (size_t)NSAMP * 6 * sizeof(double), stream);

    dim3 big(BPS, NSAMP);
    k_stats  <<<big, 256, 0, stream>>>(preds, targets, eff, hist, pos, negc);
    k_scan_hi<<<NSAMP, 256, 0, stream>>>(hist, pos, negc, bucket, rem, fb);
    k_refine <<<big, 256, 0, stream>>>(preds, targets, bucket, hist);
    k_scan_lo<<<NSAMP, 64, 0, stream>>>(hist, bucket, rem, thr);
    k_dice   <<<big, 256, 0, stream>>>(preds, targets, eff, thr, fb, sums);
    k_final  <<<1, 64, 0, stream>>>(sums, out);
}

// Round 2
// 425.389 us; speedup vs baseline: 9.2718x; 9.2718x over previous
//
#include <hip/hip_runtime.h>
#include <cstddef>

#define NSAMP 16
#define HW 409600
#define CPRED 6
#define NBINS 65536
#define BPS 100           // blocks per sample for big passes (100*256*16 = 409600)
#define EPS 1e-6

__device__ __forceinline__ unsigned sortkey(float f) {
    unsigned b = __float_as_uint(f);
    return (b & 0x80000000u) ? ~b : (b | 0x80000000u);   // larger float -> larger key
}
__device__ __forceinline__ float inv_sortkey(unsigned k) {
    unsigned b = (k & 0x80000000u) ? (k ^ 0x80000000u) : ~k;
    return __uint_as_float(b);
}
__device__ __forceinline__ float sigmoidf(float x) {
    return 1.0f / (1.0f + __expf(-x));
}

// Pass 1: pos count, neg count, hi-16-bit histogram of negative pred keys.
__global__ void k_stats(const float* __restrict__ preds,
                        const float* __restrict__ targets,
                        const float* __restrict__ eff,
                        unsigned* __restrict__ hist,
                        unsigned* __restrict__ pos,
                        unsigned* __restrict__ negc) {
    const int n = blockIdx.y;
    const float4* p4 = (const float4*)(preds + (size_t)n * CPRED * HW);
    const float4* t4 = (const float4*)(targets + (size_t)n * 2 * HW);
    const float4* e4 = (const float4*)(eff + (size_t)n * HW);
    unsigned* h = hist + (size_t)n * NBINS;
    unsigned lp = 0, ln = 0;
    const int base = blockIdx.x * 1024;
#pragma unroll
    for (int k = 0; k < 4; k++) {
        int i = base + k * 256 + threadIdx.x;
        float4 p = p4[i], t = t4[i], e = e4[i];
        float pa[4] = {p.x, p.y, p.z, p.w};
        float ta[4] = {t.x, t.y, t.z, t.w};
        float ea[4] = {e.x, e.y, e.z, e.w};
#pragma unroll
        for (int j = 0; j < 4; j++) {
            lp += (ta[j] > 0.5f && ea[j] > 0.5f) ? 1u : 0u;
            if (ta[j] <= 0.5f) {
                ln++;
                atomicAdd(&h[sortkey(pa[j]) >> 16], 1u);
            }
        }
    }
    for (int off = 32; off; off >>= 1) {
        lp += __shfl_down(lp, off, 64);
        ln += __shfl_down(ln, off, 64);
    }
    if ((threadIdx.x & 63) == 0) {
        atomicAdd(&pos[n], lp);
        atomicAdd(&negc[n], ln);
    }
}

// Pass 2: find hi bucket containing the neg_num-th largest; zero hist for reuse.
// Parallel structure: chunk sums (256 threads) -> serial scan in SHARED only.
__global__ void k_scan_hi(unsigned* __restrict__ hist,
                          const unsigned* __restrict__ pos,
                          const unsigned* __restrict__ negc,
                          unsigned* __restrict__ bucket,
                          unsigned* __restrict__ rem,
                          unsigned* __restrict__ fb) {
    const int n = blockIdx.x;
    unsigned* h = hist + (size_t)n * NBINS;
    __shared__ unsigned chunkSum[256];
    __shared__ unsigned bins[256];
    __shared__ int s_chunk;
    __shared__ unsigned long long s_cum;
    const unsigned p = pos[n], nc = negc[n];
    const unsigned long long nn =
        min((unsigned long long)p * 3ull, (unsigned long long)nc);
    const bool fallback = (p == 0) || (nn == 0);

    // phase 1: per-thread chunk sums (vectorized)
    unsigned s = 0;
    const uint4* hv4 = (const uint4*)(h + threadIdx.x * 256);
    for (int i = 0; i < 64; i++) {
        uint4 v = hv4[i];
        s += v.x + v.y + v.z + v.w;
    }
    chunkSum[threadIdx.x] = s;
    __syncthreads();

    // phase 2: thread 0 scans chunk sums in shared
    if (threadIdx.x == 0) {
        s_chunk = -1;
        if (!fallback) {
            unsigned long long cum = 0;
            int c;
            for (c = 255; c >= 0; c--) {
                if (cum + chunkSum[c] >= nn) break;
                cum += chunkSum[c];
            }
            s_chunk = c;
            s_cum = cum;
        }
    }
    __syncthreads();

    // phase 3: stage chosen chunk into shared
    if (s_chunk >= 0) bins[threadIdx.x] = h[s_chunk * 256 + threadIdx.x];
    __syncthreads();

    // phase 4: thread 0 scans bins in shared
    if (threadIdx.x == 0) {
        if (s_chunk < 0) {
            bucket[n] = 0xFFFFFFFFu;
            rem[n] = 0;
        } else {
            unsigned long long cum = s_cum;
            for (int b = 255;; b--) {
                unsigned hvv = bins[b];
                if (cum + hvv >= nn) {
                    bucket[n] = (unsigned)(s_chunk * 256 + b);
                    rem[n] = (unsigned)(nn - cum);
                    break;
                }
                cum += hvv;
            }
        }
        fb[n] = fallback ? 1u : 0u;
    }
    __syncthreads();
    // zero hist for reuse by k_refine
    uint4* hz4 = (uint4*)(h + threadIdx.x * 256);
    uint4 z = {0, 0, 0, 0};
    for (int i = 0; i < 64; i++) hz4[i] = z;
}

// Pass 3: lo-16-bit histogram for elements in the chosen hi bucket.
__global__ void k_refine(const float* __restrict__ preds,
                         const float* __restrict__ targets,
                         const unsigned* __restrict__ bucket,
                         unsigned* __restrict__ hist) {
    const int n = blockIdx.y;
    const unsigned bkt = bucket[n];
    if (bkt == 0xFFFFFFFFu) return;   // fallback sample
    const float4* p4 = (const float4*)(preds + (size_t)n * CPRED * HW);
    const float4* t4 = (const float4*)(targets + (size_t)n * 2 * HW);
    unsigned* h = hist + (size_t)n * NBINS;
    const int base = blockIdx.x * 1024;
#pragma unroll
    for (int k = 0; k < 4; k++) {
        int i = base + k * 256 + threadIdx.x;
        float4 p = p4[i], t = t4[i];
        float pa[4] = {p.x, p.y, p.z, p.w};
        float ta[4] = {t.x, t.y, t.z, t.w};
#pragma unroll
        for (int j = 0; j < 4; j++) {
            if (ta[j] <= 0.5f) {
                unsigned key = sortkey(pa[j]);
                if ((key >> 16) == bkt) atomicAdd(&h[key & 0xFFFFu], 1u);
            }
        }
    }
}

// Pass 4: exact threshold from the lo histogram (parallel scan structure).
__global__ void k_scan_lo(const unsigned* __restrict__ hist,
                          const unsigned* __restrict__ bucket,
                          const unsigned* __restrict__ rem,
                          float* __restrict__ thr) {
    const int n = blockIdx.x;
    const unsigned bkt = bucket[n];
    const unsigned* h = hist + (size_t)n * NBINS;
    __shared__ unsigned chunkSum[256];
    __shared__ unsigned bins[256];
    __shared__ int s_chunk;
    __shared__ unsigned long long s_cum;

    if (bkt == 0xFFFFFFFFu) {
        if (threadIdx.x == 0) thr[n] = -INFINITY;
        return;
    }
    const unsigned long long r = rem[n];

    unsigned s = 0;
    const uint4* hv4 = (const uint4*)(h + threadIdx.x * 256);
    for (int i = 0; i < 64; i++) {
        uint4 v = hv4[i];
        s += v.x + v.y + v.z + v.w;
    }
    chunkSum[threadIdx.x] = s;
    __syncthreads();

    if (threadIdx.x == 0) {
        unsigned long long cum = 0;
        int c;
        for (c = 255; c >= 0; c--) {
            if (cum + chunkSum[c] >= r) break;
            cum += chunkSum[c];
        }
        s_chunk = c;
        s_cum = cum;
    }
    __syncthreads();

    bins[threadIdx.x] = h[s_chunk * 256 + threadIdx.x];
    __syncthreads();

    if (threadIdx.x == 0) {
        unsigned long long cum = s_cum;
        for (int b = 255;; b--) {
            unsigned hvv = bins[b];
            if (cum + hvv >= r) {
                thr[n] = inv_sortkey((bkt << 16) | (unsigned)(s_chunk * 256 + b));
                break;
            }
            cum += hvv;
        }
    }
}

// Pass 5: fused sigmoid + masks + 6 per-sample dice sums.
__global__ void k_dice(const float* __restrict__ preds,
                       const float* __restrict__ targets,
                       const float* __restrict__ eff,
                       const float* __restrict__ thr,
                       const unsigned* __restrict__ fb,
                       double* __restrict__ sums) {
    const int n = blockIdx.y;
    const float4* p0 = (const float4*)(preds + (size_t)n * CPRED * HW);
    const float4* p1 = (const float4*)(preds + (size_t)n * CPRED * HW + HW);
    const float4* t0 = (const float4*)(targets + (size_t)n * 2 * HW);
    const float4* t1 = (const float4*)(targets + (size_t)n * 2 * HW + HW);
    const float4* e4 = (const float4*)(eff + (size_t)n * HW);
    const float th = thr[n];
    const bool fallback = fb[n] != 0;
    float sPG = 0.f, sP2 = 0.f, sG2 = 0.f, sPGk = 0.f, sP2k = 0.f, sG2k = 0.f;
    const int base = blockIdx.x * 1024;
#pragma unroll
    for (int k = 0; k < 4; k++) {
        int i = base + k * 256 + threadIdx.x;
        float4 a = p0[i], b = p1[i], t = t0[i], u = t1[i], e = e4[i];
        float pa[4] = {a.x, a.y, a.z, a.w};
        float pb[4] = {b.x, b.y, b.z, b.w};
        float ta[4] = {t.x, t.y, t.z, t.w};
        float ua[4] = {u.x, u.y, u.z, u.w};
        float ea[4] = {e.x, e.y, e.z, e.w};
#pragma unroll
        for (int j = 0; j < 4; j++) {
            float pt = sigmoidf(pa[j]);
            float pk = sigmoidf(pb[j]);
            float tbt = (ta[j] > 0.5f) ? 1.f : 0.f;
            float tbk = (ua[j] > 0.5f) ? 1.f : 0.f;
            float m;
            if (fallback) m = ea[j];
            else m = (((pa[j] >= th) || (ta[j] > 0.5f)) && (ea[j] > 0.5f)) ? 1.f : 0.f;
            float Pm = pt * m, Tm = tbt * m;
            sPG += Pm * Tm; sP2 += Pm * Pm; sG2 += Tm * Tm;
            float mk = (pt > 0.5f && ea[j] > 0.5f) ? 1.f : 0.f;
            float Pk = pk * mk, Tk = tbk * mk;
            sPGk += Pk * Tk; sP2k += Pk * Pk; sG2k += Tk * Tk;
        }
    }
    for (int off = 32; off; off >>= 1) {
        sPG  += __shfl_down(sPG, off, 64);
        sP2  += __shfl_down(sP2, off, 64);
        sG2  += __shfl_down(sG2, off, 64);
        sPGk += __shfl_down(sPGk, off, 64);
        sP2k += __shfl_down(sP2k, off, 64);
        sG2k += __shfl_down(sG2k, off, 64);
    }
    if ((threadIdx.x & 63) == 0) {
        double* s = sums + (size_t)n * 6;
        atomicAdd(&s[0], (double)sPG);
        atomicAdd(&s[1], (double)sP2);
        atomicAdd(&s[2], (double)sG2);
        atomicAdd(&s[3], (double)sPGk);
        atomicAdd(&s[4], (double)sP2k);
        atomicAdd(&s[5], (double)sG2k);
    }
}

// Pass 6: 32 outputs.
__global__ void k_final(const double* __restrict__ sums, float* __restrict__ out) {
    int n = threadIdx.x;
    if (n < NSAMP) {
        const double* s = sums + (size_t)n * 6;
        out[n]         = (float)(1.0 - 2.0 * s[0] / (s[1] + s[2] + EPS));
        out[NSAMP + n] = (float)(1.0 - 2.0 * s[3] / (s[4] + s[5] + EPS));
    }
}

extern "C" void kernel_launch(void* const* d_in, const int* in_sizes, int n_in,
                              void* d_out, int out_size, void* d_ws, size_t ws_size,
                              hipStream_t stream) {
    const float* preds = (const float*)d_in[0];
    const float* targets = (const float*)d_in[1];
    const float* eff = (const float*)d_in[2];
    float* out = (float*)d_out;

    char* ws = (char*)d_ws;
    const size_t HIST_BYTES = (size_t)NSAMP * NBINS * sizeof(unsigned);  // 4 MiB
    unsigned* hist = (unsigned*)ws;
    unsigned* pos    = (unsigned*)(ws + HIST_BYTES);         // 16 u32
    unsigned* negc   = pos + NSAMP;
    unsigned* bucket = negc + NSAMP;
    unsigned* rem    = bucket + NSAMP;
    unsigned* fb     = rem + NSAMP;
    float*    thr    = (float*)(fb + NSAMP);
    double*   sums   = (double*)(ws + HIST_BYTES + 512);     // 8-aligned, 768 B

    // zero hist + counters + sums (required every call; harness does not re-poison)
    hipMemsetAsync(d_ws, 0, HIST_BYTES + 512 + (size_t)NSAMP * 6 * sizeof(double), stream);

    dim3 big(BPS, NSAMP);
    k_stats  <<<big, 256, 0, stream>>>(preds, targets, eff, hist, pos, negc);
    k_scan_hi<<<NSAMP, 256, 0, stream>>>(hist, pos, negc, bucket, rem, fb);
    k_refine <<<big, 256, 0, stream>>>(preds, targets, bucket, hist);
    k_scan_lo<<<NSAMP, 256, 0, stream>>>(hist, bucket, rem, thr);
    k_dice   <<<big, 256, 0, stream>>>(preds, targets, eff, thr, fb, sums);
    k_final  <<<1, 64, 0, stream>>>(sums, out);
}

// Round 3
// 237.781 us; speedup vs baseline: 16.5873x; 1.7890x over previous
//
#include <hip/hip_runtime.h>
#include <cstddef>

#define NSAMP 16
#define HW 409600
#define CPRED 6
#define EPS 1e-6

#define NB1 2048      // top-11 bits
#define NB2 2048      // next-11 bits
#define NB3 1024      // low-10 bits
#define L1SHIFT 21
#define BPSH 50       // blocks/sample, histogram passes (50*256*32 = 409600)
#define BPSD 100      // blocks/sample, dice pass

__device__ __forceinline__ unsigned sortkey(float f) {
    unsigned b = __float_as_uint(f);
    return (b & 0x80000000u) ? ~b : (b | 0x80000000u);   // larger float -> larger key
}
__device__ __forceinline__ float inv_sortkey(unsigned k) {
    unsigned b = (k & 0x80000000u) ? (k ^ 0x80000000u) : ~k;
    return __uint_as_float(b);
}
__device__ __forceinline__ float sigmoidf(float x) {
    return 1.0f / (1.0f + __expf(-x));
}

// Pass 1: pos, neg counts + level-1 histogram (LDS per-wave copies, sparse flush).
__global__ void k_stats(const float* __restrict__ preds,
                        const float* __restrict__ targets,
                        const float* __restrict__ eff,
                        unsigned* __restrict__ hist,
                        unsigned* __restrict__ pos,
                        unsigned* __restrict__ negc) {
    const int n = blockIdx.y;
    const float4* p4 = (const float4*)(preds + (size_t)n * CPRED * HW);
    const float4* t4 = (const float4*)(targets + (size_t)n * 2 * HW);
    const float4* e4 = (const float4*)(eff + (size_t)n * HW);
    __shared__ unsigned h[4][NB1];
    for (int i = threadIdx.x; i < 4 * NB1; i += 256) ((unsigned*)h)[i] = 0;
    __syncthreads();
    const int wave = threadIdx.x >> 6;
    unsigned lp = 0, ln = 0;
    const int base = blockIdx.x * 2048;   // float4 units; 8192 floats/block
#pragma unroll
    for (int k = 0; k < 8; k++) {
        int i = base + k * 256 + threadIdx.x;
        float4 p = p4[i], t = t4[i], e = e4[i];
        float pa[4] = {p.x, p.y, p.z, p.w};
        float ta[4] = {t.x, t.y, t.z, t.w};
        float ea[4] = {e.x, e.y, e.z, e.w};
#pragma unroll
        for (int j = 0; j < 4; j++) {
            lp += (ta[j] > 0.5f && ea[j] > 0.5f) ? 1u : 0u;
            if (ta[j] <= 0.5f) {
                ln++;
                atomicAdd(&h[wave][sortkey(pa[j]) >> L1SHIFT], 1u);
            }
        }
    }
    for (int off = 32; off; off >>= 1) {
        lp += __shfl_down(lp, off, 64);
        ln += __shfl_down(ln, off, 64);
    }
    if ((threadIdx.x & 63) == 0) {
        atomicAdd(&pos[n], lp);
        atomicAdd(&negc[n], ln);
    }
    __syncthreads();
    unsigned* gh = hist + (size_t)n * NB1;
    for (int b = threadIdx.x; b < NB1; b += 256) {
        unsigned s = h[0][b] + h[1][b] + h[2][b] + h[3][b];
        if (s) atomicAdd(&gh[b], s);
    }
}

// Generic per-sample descending scan over staged LDS bins (t0 serial in shared).
// Returns via pointers; also zeroes the global hist region for the next level.
__global__ void k_scan1(unsigned* __restrict__ hist,
                        const unsigned* __restrict__ pos,
                        const unsigned* __restrict__ negc,
                        unsigned* __restrict__ b1,
                        unsigned* __restrict__ rem1,
                        unsigned* __restrict__ fb) {
    const int n = blockIdx.x;
    unsigned* gh = hist + (size_t)n * NB1;
    __shared__ unsigned bins[NB1];
    __shared__ unsigned chunkSum[256];
    for (int i = threadIdx.x; i < NB1; i += 256) bins[i] = gh[i];
    __syncthreads();
    for (int i = threadIdx.x; i < NB1; i += 256) gh[i] = 0;   // reuse for level 2
    unsigned s = 0;
#pragma unroll
    for (int j = 0; j < 8; j++) s += bins[threadIdx.x * 8 + j];
    chunkSum[threadIdx.x] = s;
    __syncthreads();
    if (threadIdx.x == 0) {
        const unsigned p = pos[n], nc = negc[n];
        const unsigned nn = min(p * 3u, nc);
        if (p == 0 || nn == 0) {
            b1[n] = 0xFFFFFFFFu; rem1[n] = 0; fb[n] = 1u;
        } else {
            fb[n] = 0u;
            unsigned cum = 0;
            int c;
            for (c = 255;; c--) {
                if (cum + chunkSum[c] >= nn) break;
                cum += chunkSum[c];
            }
            int b;
            for (b = c * 8 + 7;; b--) {
                unsigned hv = bins[b];
                if (cum + hv >= nn) break;
                cum += hv;
            }
            b1[n] = (unsigned)b;
            rem1[n] = nn - cum;
        }
    }
}

// Level-2 histogram: next 11 bits for elements whose top-11 == b1.
__global__ void k_refine2(const float* __restrict__ preds,
                          const float* __restrict__ targets,
                          const unsigned* __restrict__ b1,
                          unsigned* __restrict__ hist) {
    const int n = blockIdx.y;
    const unsigned B1 = b1[n];
    if (B1 == 0xFFFFFFFFu) return;
    const float4* p4 = (const float4*)(preds + (size_t)n * CPRED * HW);
    const float4* t4 = (const float4*)(targets + (size_t)n * 2 * HW);
    __shared__ unsigned h[4][NB2];
    for (int i = threadIdx.x; i < 4 * NB2; i += 256) ((unsigned*)h)[i] = 0;
    __syncthreads();
    const int wave = threadIdx.x >> 6;
    const int base = blockIdx.x * 2048;
#pragma unroll
    for (int k = 0; k < 8; k++) {
        int i = base + k * 256 + threadIdx.x;
        float4 p = p4[i], t = t4[i];
        float pa[4] = {p.x, p.y, p.z, p.w};
        float ta[4] = {t.x, t.y, t.z, t.w};
#pragma unroll
        for (int j = 0; j < 4; j++) {
            if (ta[j] <= 0.5f) {
                unsigned key = sortkey(pa[j]);
                if ((key >> L1SHIFT) == B1)
                    atomicAdd(&h[wave][(key >> 10) & 0x7FFu], 1u);
            }
        }
    }
    __syncthreads();
    unsigned* gh = hist + (size_t)n * NB1;
    for (int b = threadIdx.x; b < NB2; b += 256) {
        unsigned s = h[0][b] + h[1][b] + h[2][b] + h[3][b];
        if (s) atomicAdd(&gh[b], s);
    }
}

__global__ void k_scan2(unsigned* __restrict__ hist,
                        const unsigned* __restrict__ fb,
                        const unsigned* __restrict__ rem1,
                        unsigned* __restrict__ b2,
                        unsigned* __restrict__ rem2) {
    const int n = blockIdx.x;
    unsigned* gh = hist + (size_t)n * NB1;
    __shared__ unsigned bins[NB2];
    __shared__ unsigned chunkSum[256];
    for (int i = threadIdx.x; i < NB2; i += 256) bins[i] = gh[i];
    __syncthreads();
    for (int i = threadIdx.x; i < NB2; i += 256) gh[i] = 0;   // reuse for level 3
    unsigned s = 0;
#pragma unroll
    for (int j = 0; j < 8; j++) s += bins[threadIdx.x * 8 + j];
    chunkSum[threadIdx.x] = s;
    __syncthreads();
    if (threadIdx.x == 0) {
        if (fb[n]) { b2[n] = 0; rem2[n] = 0; return; }
        const unsigned r = rem1[n];
        unsigned cum = 0;
        int c;
        for (c = 255;; c--) {
            if (cum + chunkSum[c] >= r) break;
            cum += chunkSum[c];
        }
        int b;
        for (b = c * 8 + 7;; b--) {
            unsigned hv = bins[b];
            if (cum + hv >= r) break;
            cum += hv;
        }
        b2[n] = (unsigned)b;
        rem2[n] = r - cum;
    }
}

// Level-3 histogram: low 10 bits for elements whose top-22 match.
__global__ void k_refine3(const float* __restrict__ preds,
                          const float* __restrict__ targets,
                          const unsigned* __restrict__ b1,
                          const unsigned* __restrict__ b2,
                          unsigned* __restrict__ hist) {
    const int n = blockIdx.y;
    const unsigned B1 = b1[n];
    if (B1 == 0xFFFFFFFFu) return;
    const unsigned prefix = (B1 << 11) | b2[n];   // 22-bit prefix
    const float4* p4 = (const float4*)(preds + (size_t)n * CPRED * HW);
    const float4* t4 = (const float4*)(targets + (size_t)n * 2 * HW);
    __shared__ unsigned h[4][NB3];
    for (int i = threadIdx.x; i < 4 * NB3; i += 256) ((unsigned*)h)[i] = 0;
    __syncthreads();
    const int wave = threadIdx.x >> 6;
    const int base = blockIdx.x * 2048;
#pragma unroll
    for (int k = 0; k < 8; k++) {
        int i = base + k * 256 + threadIdx.x;
        float4 p = p4[i], t = t4[i];
        float pa[4] = {p.x, p.y, p.z, p.w};
        float ta[4] = {t.x, t.y, t.z, t.w};
#pragma unroll
        for (int j = 0; j < 4; j++) {
            if (ta[j] <= 0.5f) {
                unsigned key = sortkey(pa[j]);
                if ((key >> 10) == prefix)
                    atomicAdd(&h[wave][key & 0x3FFu], 1u);
            }
        }
    }
    __syncthreads();
    unsigned* gh = hist + (size_t)n * NB1;
    for (int b = threadIdx.x; b < NB3; b += 256) {
        unsigned s = h[0][b] + h[1][b] + h[2][b] + h[3][b];
        if (s) atomicAdd(&gh[b], s);
    }
}

__global__ void k_scan3(const unsigned* __restrict__ hist,
                        const unsigned* __restrict__ fb,
                        const unsigned* __restrict__ b1,
                        const unsigned* __restrict__ b2,
                        const unsigned* __restrict__ rem2,
                        float* __restrict__ thr) {
    const int n = blockIdx.x;
    const unsigned* gh = hist + (size_t)n * NB1;
    __shared__ unsigned bins[NB3];
    __shared__ unsigned chunkSum[256];
    for (int i = threadIdx.x; i < NB3; i += 256) bins[i] = gh[i];
    __syncthreads();
    unsigned s = 0;
#pragma unroll
    for (int j = 0; j < 4; j++) s += bins[threadIdx.x * 4 + j];
    chunkSum[threadIdx.x] = s;
    __syncthreads();
    if (threadIdx.x == 0) {
        if (fb[n]) { thr[n] = -INFINITY; return; }
        const unsigned r = rem2[n];
        unsigned cum = 0;
        int c;
        for (c = 255;; c--) {
            if (cum + chunkSum[c] >= r) break;
            cum += chunkSum[c];
        }
        int b;
        for (b = c * 4 + 3;; b--) {
            unsigned hv = bins[b];
            if (cum + hv >= r) break;
            cum += hv;
        }
        thr[n] = inv_sortkey((b1[n] << L1SHIFT) | (b2[n] << 10) | (unsigned)b);
    }
}

// Pass 5: fused sigmoid + masks + 6 per-sample dice sums.
__global__ void k_dice(const float* __restrict__ preds,
                       const float* __restrict__ targets,
                       const float* __restrict__ eff,
                       const float* __restrict__ thr,
                       const unsigned* __restrict__ fb,
                       double* __restrict__ sums) {
    const int n = blockIdx.y;
    const float4* p0 = (const float4*)(preds + (size_t)n * CPRED * HW);
    const float4* p1 = (const float4*)(preds + (size_t)n * CPRED * HW + HW);
    const float4* t0 = (const float4*)(targets + (size_t)n * 2 * HW);
    const float4* t1 = (const float4*)(targets + (size_t)n * 2 * HW + HW);
    const float4* e4 = (const float4*)(eff + (size_t)n * HW);
    const float th = thr[n];
    const bool fallback = fb[n] != 0;
    float sPG = 0.f, sP2 = 0.f, sG2 = 0.f, sPGk = 0.f, sP2k = 0.f, sG2k = 0.f;
    const int base = blockIdx.x * 1024;
#pragma unroll
    for (int k = 0; k < 4; k++) {
        int i = base + k * 256 + threadIdx.x;
        float4 a = p0[i], b = p1[i], t = t0[i], u = t1[i], e = e4[i];
        float pa[4] = {a.x, a.y, a.z, a.w};
        float pb[4] = {b.x, b.y, b.z, b.w};
        float ta[4] = {t.x, t.y, t.z, t.w};
        float ua[4] = {u.x, u.y, u.z, u.w};
        float ea[4] = {e.x, e.y, e.z, e.w};
#pragma unroll
        for (int j = 0; j < 4; j++) {
            float pt = sigmoidf(pa[j]);
            float pk = sigmoidf(pb[j]);
            float tbt = (ta[j] > 0.5f) ? 1.f : 0.f;
            float tbk = (ua[j] > 0.5f) ? 1.f : 0.f;
            float m;
            if (fallback) m = ea[j];
            else m = (((pa[j] >= th) || (ta[j] > 0.5f)) && (ea[j] > 0.5f)) ? 1.f : 0.f;
            float Pm = pt * m, Tm = tbt * m;
            sPG += Pm * Tm; sP2 += Pm * Pm; sG2 += Tm * Tm;
            float mk = (pt > 0.5f && ea[j] > 0.5f) ? 1.f : 0.f;
            float Pk = pk * mk, Tk = tbk * mk;
            sPGk += Pk * Tk; sP2k += Pk * Pk; sG2k += Tk * Tk;
        }
    }
    for (int off = 32; off; off >>= 1) {
        sPG  += __shfl_down(sPG, off, 64);
        sP2  += __shfl_down(sP2, off, 64);
        sG2  += __shfl_down(sG2, off, 64);
        sPGk += __shfl_down(sPGk, off, 64);
        sP2k += __shfl_down(sP2k, off, 64);
        sG2k += __shfl_down(sG2k, off, 64);
    }
    if ((threadIdx.x & 63) == 0) {
        double* s = sums + (size_t)n * 6;
        atomicAdd(&s[0], (double)sPG);
        atomicAdd(&s[1], (double)sP2);
        atomicAdd(&s[2], (double)sG2);
        atomicAdd(&s[3], (double)sPGk);
        atomicAdd(&s[4], (double)sP2k);
        atomicAdd(&s[5], (double)sG2k);
    }
}

__global__ void k_final(const double* __restrict__ sums, float* __restrict__ out) {
    int n = threadIdx.x;
    if (n < NSAMP) {
        const double* s = sums + (size_t)n * 6;
        out[n]         = (float)(1.0 - 2.0 * s[0] / (s[1] + s[2] + EPS));
        out[NSAMP + n] = (float)(1.0 - 2.0 * s[3] / (s[4] + s[5] + EPS));
    }
}

extern "C" void kernel_launch(void* const* d_in, const int* in_sizes, int n_in,
                              void* d_out, int out_size, void* d_ws, size_t ws_size,
                              hipStream_t stream) {
    const float* preds = (const float*)d_in[0];
    const float* targets = (const float*)d_in[1];
    const float* eff = (const float*)d_in[2];
    float* out = (float*)d_out;

    char* ws = (char*)d_ws;
    const size_t HIST_BYTES = (size_t)NSAMP * NB1 * sizeof(unsigned);  // 128 KiB
    unsigned* hist = (unsigned*)ws;
    unsigned* pos  = (unsigned*)(ws + HIST_BYTES);
    unsigned* negc = pos + NSAMP;
    unsigned* b1   = negc + NSAMP;
    unsigned* b2   = b1 + NSAMP;
    unsigned* rem1 = b2 + NSAMP;
    unsigned* rem2 = rem1 + NSAMP;
    unsigned* fb   = rem2 + NSAMP;
    float*    thr  = (float*)(fb + NSAMP);                    // 8 arrays * 64B = 512B
    double*   sums = (double*)(ws + HIST_BYTES + 512);        // 768 B

    // zero hist + counters + sums every call
    hipMemsetAsync(d_ws, 0, HIST_BYTES + 512 + (size_t)NSAMP * 6 * sizeof(double), stream);

    dim3 bh(BPSH, NSAMP);
    dim3 bd(BPSD, NSAMP);
    k_stats  <<<bh, 256, 0, stream>>>(preds, targets, eff, hist, pos, negc);
    k_scan1  <<<NSAMP, 256, 0, stream>>>(hist, pos, negc, b1, rem1, fb);
    k_refine2<<<bh, 256, 0, stream>>>(preds, targets, b1, hist);
    k_scan2  <<<NSAMP, 256, 0, stream>>>(hist, fb, rem1, b2, rem2);
    k_refine3<<<bh, 256, 0, stream>>>(preds, targets, b1, b2, hist);
    k_scan3  <<<NSAMP, 256, 0, stream>>>(hist, fb, b1, b2, rem2, thr);
    k_dice   <<<bd, 256, 0, stream>>>(preds, targets, eff, thr, fb, sums);
    k_final  <<<1, 64, 0, stream>>>(sums, out);
}